// Round 2
// baseline (39.970 us; speedup 1.0000x reference)
//
#include <hip/hip_runtime.h>
#include <math.h>

#define KS     3
#define ALPHA  0.1f
#define M      56
#define N      56
#define L      18
#define KK     18
#define PIX    (M * N)        // 3136
#define VEC    (PIX / 4)      // 784
#define NTHR   256
#define COVER  (L * KS)       // 54

__device__ __forceinline__ float4 process4(float4 x, int v, float peak, size_t base,
                                           const int* __restrict__ rc,
                                           const int* smask) {
    const int p0 = v * 4;
    const int i  = p0 / N;          // all 4 elems share the row (56 % 4 == 0)
    const int j0 = p0 - i * N;
    const bool inrow = (i < COVER);
    const int  mrow  = (i / 3) * KK;

    float vals[4] = {x.x, x.y, x.z, x.w};
    float o[4];
#pragma unroll
    for (int e = 0; e < 4; ++e) {
        const float a = vals[e];
        const int   j = j0 + e;
        bool cond;
        if (a == peak) {
            // peak pixel: decision comes from rc only (bc_dd term is zeroed)
            cond = (rc[base + (size_t)(p0 + e)] != 0);
        } else {
            // non-peak: patch-level bernoulli mask over covered 54x54 region
            cond = inrow && (j < COVER) && (smask[mrow + j / 3] != 0);
        }
        o[e] = cond ? a * ALPHA : a;
    }
    return make_float4(o[0], o[1], o[2], o[3]);
}

__global__ __launch_bounds__(NTHR) void div_block_kernel(
    const float* __restrict__ act,
    const int*   __restrict__ rc,
    const int*   __restrict__ pmask,
    float*       __restrict__ out) {

    const int    plane = blockIdx.x;            // b*c plane index
    const int    tid   = threadIdx.x;
    const size_t base  = (size_t)plane * PIX;

    const float4* a4 = (const float4*)(act + base);
    float4*       o4 = (float4*)(out + base);

    __shared__ int   smask[L * KK];             // 324 ints
    __shared__ float wmax[NTHR / 64];
    __shared__ float peak_s;

    // FIX: 324 entries > 256 threads — must stride, else smask[256..323] is garbage
    for (int s = tid; s < L * KK; s += NTHR)
        smask[s] = pmask[(size_t)plane * (L * KK) + s];

    // ---- load plane into registers (named, no scratch), local max ----
    const int v0 = tid, v1 = tid + NTHR, v2 = tid + 2 * NTHR, v3 = tid + 3 * NTHR;
    float4 x0 = a4[v0];
    float4 x1 = a4[v1];
    float4 x2 = a4[v2];
    const bool has3 = (v3 < VEC);               // tid < 16
    float4 x3 = has3 ? a4[v3]
                     : make_float4(-INFINITY, -INFINITY, -INFINITY, -INFINITY);

    float lmax = fmaxf(fmaxf(x0.x, x0.y), fmaxf(x0.z, x0.w));
    lmax = fmaxf(lmax, fmaxf(fmaxf(x1.x, x1.y), fmaxf(x1.z, x1.w)));
    lmax = fmaxf(lmax, fmaxf(fmaxf(x2.x, x2.y), fmaxf(x2.z, x2.w)));
    lmax = fmaxf(lmax, fmaxf(fmaxf(x3.x, x3.y), fmaxf(x3.z, x3.w)));

    // ---- wave (64-lane) butterfly max, then cross-wave via LDS ----
#pragma unroll
    for (int off = 32; off > 0; off >>= 1)
        lmax = fmaxf(lmax, __shfl_xor(lmax, off, 64));
    if ((tid & 63) == 0)
        wmax[tid >> 6] = lmax;
    __syncthreads();
    if (tid == 0)
        peak_s = fmaxf(fmaxf(wmax[0], wmax[1]), fmaxf(wmax[2], wmax[3]));
    __syncthreads();
    const float peak = peak_s;

    // ---- apply decision + write ----
    o4[v0] = process4(x0, v0, peak, base, rc, smask);
    o4[v1] = process4(x1, v1, peak, base, rc, smask);
    o4[v2] = process4(x2, v2, peak, base, rc, smask);
    if (has3)
        o4[v3] = process4(x3, v3, peak, base, rc, smask);
}

extern "C" void kernel_launch(void* const* d_in, const int* in_sizes, int n_in,
                              void* d_out, int out_size, void* d_ws, size_t ws_size,
                              hipStream_t stream) {
    const float* act   = (const float*)d_in[0];
    const int*   rc    = (const int*)d_in[1];
    const int*   pmask = (const int*)d_in[2];
    float*       out   = (float*)d_out;

    const int planes = in_sizes[0] / PIX;       // 32*256 = 8192
    div_block_kernel<<<planes, NTHR, 0, stream>>>(act, rc, pmask, out);
}